// Round 13
// baseline (695.186 us; speedup 1.0000x reference)
//
#include <hip/hip_runtime.h>

// ---------------- problem constants ----------------
#define S_   2048
#define DM   512
#define HD   64
#define BHN  32

typedef unsigned short u16;
typedef __bf16 bf16x8 __attribute__((ext_vector_type(8)));
typedef float  f32x4  __attribute__((ext_vector_type(4)));

__device__ __forceinline__ float bf2f(u16 u) {
    union { unsigned int i; float f; } v; v.i = ((unsigned int)u) << 16; return v.f;
}
__device__ __forceinline__ u16 f2bf(float f) {
    union { float f; unsigned int i; } v; v.f = f;
    unsigned int i = v.i;
    return (u16)((i + 0x7FFFu + ((i >> 16) & 1u)) >> 16);   // RNE
}
// 3-term bf16 split: x ~= b0+b1+b2 (residual ~2^-27 |x|)
__device__ __forceinline__ void split3(float x, u16& b0, u16& b1, u16& b2) {
    b0 = f2bf(x);
    const float r0 = x - bf2f(b0);
    b1 = f2bf(r0);
    const float r1 = r0 - bf2f(b1);
    b2 = f2bf(r1);
}

// ---------------- prep: W[k][n] fp32 -> transposed bf16 splits [n][k] ----------------
__global__ __launch_bounds__(256) void prep_split_wT(
    const float* __restrict__ W, int N, int total,
    u16* __restrict__ w0, u16* __restrict__ w1, u16* __restrict__ w2)
{
    for (int idx = blockIdx.x * 256 + threadIdx.x; idx < total; idx += gridDim.x * 256) {
        const int n = idx >> 9, k = idx & 511;      // K = 512
        u16 a0, a1, a2;
        split3(W[(size_t)k * N + n], a0, a1, a2);
        w0[idx] = a0; w1[idx] = a1;
        if (w2) w2[idx] = a2;
    }
}

// ---------------- QKV GEMM: MFMA, 3-split x, 3-split W^T ----------------
// fastmode=1: k -> bf16 splits k0/k1/k2.  fastmode=0: k -> fp32 kh.
__global__ __launch_bounds__(256) void gemm_qkv_mfma(
    const float* __restrict__ A, const u16* __restrict__ Wt0, const u16* __restrict__ Wt1,
    const u16* __restrict__ Wt2, const float* __restrict__ bias,
    float* __restrict__ qh, float* __restrict__ kh,
    u16* __restrict__ k0g, u16* __restrict__ k1g, u16* __restrict__ k2g,
    u16* __restrict__ vt, int fastmode)
{
    __shared__ __attribute__((aligned(16))) u16 As0[128 * 32], As1[128 * 32], As2[128 * 32];
    __shared__ __attribute__((aligned(16))) u16 Bs0[128 * 32], Bs1[128 * 32], Bs2[128 * 32];

    const int t  = threadIdx.x;
    const int m0 = blockIdx.y * 128, n0 = blockIdx.x * 128;
    const int w  = t >> 6, l = t & 63;
    const int wm = (w >> 1) * 64, wn = (w & 1) * 64;
    const int lr = l & 15, lq = l >> 4;

    const f32x4 zero4 = {0.f, 0.f, 0.f, 0.f};
    f32x4 acc[4][4];
#pragma unroll
    for (int i = 0; i < 4; i++)
#pragma unroll
        for (int j = 0; j < 4; j++) acc[i][j] = zero4;

    for (int k0 = 0; k0 < 512; k0 += 32) {
        __syncthreads();
#pragma unroll
        for (int i = 0; i < 4; i++) {
            const int e = t + 256 * i;
            const int r = e >> 3, c4 = (e & 7) * 4;
            const float4 f = *(const float4*)(&A[(size_t)(m0 + r) * 512 + k0 + c4]);
            const float xv[4] = {f.x, f.y, f.z, f.w};
            u16 a0[4], a1[4], a2[4];
#pragma unroll
            for (int j = 0; j < 4; j++) split3(xv[j], a0[j], a1[j], a2[j]);
            int2 p0, p1, p2;
            p0.x = a0[0] | (a0[1] << 16); p0.y = a0[2] | (a0[3] << 16);
            p1.x = a1[0] | (a1[1] << 16); p1.y = a1[2] | (a1[3] << 16);
            p2.x = a2[0] | (a2[1] << 16); p2.y = a2[2] | (a2[3] << 16);
            *(int2*)(&As0[r * 32 + c4]) = p0;
            *(int2*)(&As1[r * 32 + c4]) = p1;
            *(int2*)(&As2[r * 32 + c4]) = p2;
        }
#pragma unroll
        for (int i = 0; i < 2; i++) {
            const int e = t + 256 * i;
            const int r = e >> 2, c0 = (e & 3) * 8;
            *(int4*)(&Bs0[r * 32 + c0]) = *(const int4*)(&Wt0[(size_t)(n0 + r) * 512 + k0 + c0]);
            *(int4*)(&Bs1[r * 32 + c0]) = *(const int4*)(&Wt1[(size_t)(n0 + r) * 512 + k0 + c0]);
            *(int4*)(&Bs2[r * 32 + c0]) = *(const int4*)(&Wt2[(size_t)(n0 + r) * 512 + k0 + c0]);
        }
        __syncthreads();

#pragma unroll
        for (int i = 0; i < 4; i++) {
            const int ao = (wm + i * 16 + lr) * 32 + lq * 8;
            const bf16x8 a0 = *(const bf16x8*)(&As0[ao]);
            const bf16x8 a1 = *(const bf16x8*)(&As1[ao]);
            const bf16x8 a2 = *(const bf16x8*)(&As2[ao]);
#pragma unroll
            for (int j = 0; j < 4; j++) {
                const int bo = (wn + j * 16 + lr) * 32 + lq * 8;
                const bf16x8 b0 = *(const bf16x8*)(&Bs0[bo]);
                const bf16x8 b1 = *(const bf16x8*)(&Bs1[bo]);
                const bf16x8 b2 = *(const bf16x8*)(&Bs2[bo]);
                f32x4 c = acc[i][j];
                c = __builtin_amdgcn_mfma_f32_16x16x32_bf16(a0, b0, c, 0, 0, 0);
                c = __builtin_amdgcn_mfma_f32_16x16x32_bf16(a0, b1, c, 0, 0, 0);
                c = __builtin_amdgcn_mfma_f32_16x16x32_bf16(a1, b0, c, 0, 0, 0);
                c = __builtin_amdgcn_mfma_f32_16x16x32_bf16(a1, b1, c, 0, 0, 0);
                c = __builtin_amdgcn_mfma_f32_16x16x32_bf16(a0, b2, c, 0, 0, 0);
                c = __builtin_amdgcn_mfma_f32_16x16x32_bf16(a2, b0, c, 0, 0, 0);
                acc[i][j] = c;
            }
        }
    }

#pragma unroll
    for (int j = 0; j < 4; j++) {
        const int n = n0 + wn + j * 16 + lr;
        const float bv = bias[n];
        const int part = n >> 9, within = n & 511;
        const int h = within >> 6, d = within & 63;
#pragma unroll
        for (int i = 0; i < 4; i++) {
#pragma unroll
            for (int r = 0; r < 4; r++) {
                const int m = m0 + wm + i * 16 + lq * 4 + r;
                const int b = m >> 11, ns = m & 2047;
                const float val = acc[i][j][r] + bv;
                if (part == 0) {
                    qh[(((size_t)(b * 8 + h)) * S_ + ns) * HD + d] = val;
                } else if (part == 1) {
                    const size_t off = (((size_t)(b * 8 + h)) * S_ + ns) * HD + d;
                    if (fastmode) {
                        u16 s0, s1, s2;
                        split3(val, s0, s1, s2);
                        k0g[off] = s0; k1g[off] = s1; k2g[off] = s2;
                    } else {
                        kh[off] = val;
                    }
                } else {
                    vt[(((size_t)(b * 8 + h)) * HD + d) * S_ + ns] = f2bf(val);
                }
            }
        }
    }
}

#define LDH 72

// ---------------- fast attention: K-splits precomputed (pure-copy staging) ----------------
__global__ __launch_bounds__(256) void attn_pre(
    const float* __restrict__ q_ws,
    const u16* __restrict__ k0g, const u16* __restrict__ k1g, const u16* __restrict__ k2g,
    const u16* __restrict__ vt_ws, u16* __restrict__ ao_ws)
{
    __shared__ __attribute__((aligned(16))) u16 K0s[64 * LDH], K1s[64 * LDH], K2s[64 * LDH];
    __shared__ __attribute__((aligned(16))) u16 Vs[64 * LDH];
    __shared__ __attribute__((aligned(16))) u16 Ps[4][16 * LDH];

    const int t  = threadIdx.x;
    const int w  = t >> 6, l = t & 63;
    const int lr = l & 15, lq = l >> 4;
    const int bh = blockIdx.y, b = bh >> 3, h = bh & 7;
    const int q0 = blockIdx.x * 64;

    const float* qg = q_ws + ((size_t)bh * S_ + q0) * HD;
    const u16* kb0 = k0g + (size_t)bh * S_ * HD;
    const u16* kb1 = k1g + (size_t)bh * S_ * HD;
    const u16* kb2 = k2g + (size_t)bh * S_ * HD;
    const u16* vb  = vt_ws + (size_t)bh * HD * S_;

    // ---- stage Q 3-split (scale 0.125 folded, exact pow2) into K buffers ----
#pragma unroll
    for (int i = 0; i < 4; i++) {
        const int e = t + 256 * i;
        const int row = e >> 4, c0 = (e & 15) * 4;
        const float4 f = *(const float4*)(qg + (size_t)e * 4);
        const float xv[4] = {f.x * 0.125f, f.y * 0.125f, f.z * 0.125f, f.w * 0.125f};
        u16 a0[4], a1[4], a2[4];
#pragma unroll
        for (int j = 0; j < 4; j++) split3(xv[j], a0[j], a1[j], a2[j]);
        int2 p0, p1, p2;
        p0.x = a0[0] | (a0[1] << 16); p0.y = a0[2] | (a0[3] << 16);
        p1.x = a1[0] | (a1[1] << 16); p1.y = a1[2] | (a1[3] << 16);
        p2.x = a2[0] | (a2[1] << 16); p2.y = a2[2] | (a2[3] << 16);
        *(int2*)(&K0s[row * LDH + c0]) = p0;
        *(int2*)(&K1s[row * LDH + c0]) = p1;
        *(int2*)(&K2s[row * LDH + c0]) = p2;
    }
    __syncthreads();

    bf16x8 fq0[2], fq1[2], fq2[2];
#pragma unroll
    for (int kc = 0; kc < 2; kc++) {
        const int o = (w * 16 + lr) * LDH + kc * 32 + lq * 8;
        fq0[kc] = *(const bf16x8*)(&K0s[o]);
        fq1[kc] = *(const bf16x8*)(&K1s[o]);
        fq2[kc] = *(const bf16x8*)(&K2s[o]);
    }

    const f32x4 zero4 = {0.f, 0.f, 0.f, 0.f};
    double lsum[4] = {0.0, 0.0, 0.0, 0.0};

    // ---- pass A: denominator; staging = pure int4 copies ----
    for (int jt = 0; jt < 32; jt++) {
        __syncthreads();
        const size_t kof = (size_t)jt * 64 * HD;   // contiguous 64x64 u16
#pragma unroll
        for (int i = 0; i < 2; i++) {
            const int e = t + 256 * i;             // 512 int4s
            const int r = e >> 3, c0 = (e & 7) * 8;
            *(int4*)(&K0s[r * LDH + c0]) = *(const int4*)(&kb0[kof + (size_t)e * 8]);
            *(int4*)(&K1s[r * LDH + c0]) = *(const int4*)(&kb1[kof + (size_t)e * 8]);
            *(int4*)(&K2s[r * LDH + c0]) = *(const int4*)(&kb2[kof + (size_t)e * 8]);
        }
        __syncthreads();

#pragma unroll
        for (int nt = 0; nt < 4; nt++) {
            f32x4 aHH = zero4, aC = zero4;
#pragma unroll
            for (int kc = 0; kc < 2; kc++) {
                const int ko = (nt * 16 + lr) * LDH + kc * 32 + lq * 8;
                const bf16x8 k0 = *(const bf16x8*)(&K0s[ko]);
                const bf16x8 k1 = *(const bf16x8*)(&K1s[ko]);
                const bf16x8 k2 = *(const bf16x8*)(&K2s[ko]);
                aHH = __builtin_amdgcn_mfma_f32_16x16x32_bf16(fq0[kc], k0, aHH, 0, 0, 0);
                aC  = __builtin_amdgcn_mfma_f32_16x16x32_bf16(fq0[kc], k1, aC, 0, 0, 0);
                aC  = __builtin_amdgcn_mfma_f32_16x16x32_bf16(fq1[kc], k0, aC, 0, 0, 0);
                aC  = __builtin_amdgcn_mfma_f32_16x16x32_bf16(fq1[kc], k1, aC, 0, 0, 0);
                aC  = __builtin_amdgcn_mfma_f32_16x16x32_bf16(fq0[kc], k2, aC, 0, 0, 0);
                aC  = __builtin_amdgcn_mfma_f32_16x16x32_bf16(fq2[kc], k0, aC, 0, 0, 0);
            }
#pragma unroll
            for (int r = 0; r < 4; r++) {
                const float s = fminf(fmaxf(aHH[r] + aC[r], -30.f), 30.f);
                lsum[r] += (double)__expf(s);
            }
        }
    }
#pragma unroll
    for (int r = 0; r < 4; r++) {
#pragma unroll
        for (int off = 1; off < 16; off <<= 1)
            lsum[r] += __shfl_xor(lsum[r], off, 64);
    }
    double l_d[4]; float inv_l[4];
#pragma unroll
    for (int r = 0; r < 4; r++) { l_d[r] = lsum[r]; inv_l[r] = (float)(1.0 / lsum[r]); }

    f32x4 oacc[4];
#pragma unroll
    for (int dt = 0; dt < 4; dt++) oacc[dt] = zero4;

    // ---- pass B: bf16 scores (k0 copy), band [0.009,0.0115] -> fp64 refine, MFMA PV ----
    for (int jt = 0; jt < 32; jt++) {
        __syncthreads();
        const size_t kof = (size_t)jt * 64 * HD;
#pragma unroll
        for (int i = 0; i < 2; i++) {
            const int e = t + 256 * i;
            const int r = e >> 3, c0 = (e & 7) * 8;
            *(int4*)(&K0s[r * LDH + c0]) = *(const int4*)(&kb0[kof + (size_t)e * 8]);
            *(int4*)(&Vs[r * LDH + c0])  = *(const int4*)(&vb[(size_t)r * S_ + jt * 64 + c0]);
        }
        __syncthreads();

#pragma unroll
        for (int nt = 0; nt < 4; nt++) {
            f32x4 sacc = zero4;
#pragma unroll
            for (int kc = 0; kc < 2; kc++) {
                const bf16x8 k0 = *(const bf16x8*)(&K0s[(nt * 16 + lr) * LDH + kc * 32 + lq * 8]);
                sacc = __builtin_amdgcn_mfma_f32_16x16x32_bf16(fq0[kc], k0, sacc, 0, 0, 0);
            }
#pragma unroll
            for (int r = 0; r < 4; r++) {
                const float s = fminf(fmaxf(sacc[r], -30.f), 30.f);
                const float p = __expf(s) * inv_l[r];
                u16 pb;
                if (p > 0.0115f) {
                    pb = f2bf(p);
                } else if (p < 0.009f) {
                    pb = 0;
                } else {
                    const int row = q0 + w * 16 + lq * 4 + r;
                    const int col = jt * 64 + nt * 16 + lr;
                    const float* qr = q_ws + ((size_t)bh * S_ + row) * HD;
                    const size_t kc0 = ((size_t)bh * S_ + col) * HD;
                    double s64 = 0.0;
                    for (int d = 0; d < HD; d++) {
                        const double kd = (double)bf2f(k0g[kc0 + d]) + (double)bf2f(k1g[kc0 + d])
                                        + (double)bf2f(k2g[kc0 + d]);
                        s64 += (double)qr[d] * kd;
                    }
                    s64 = fmin(fmax(s64 * 0.125, -30.0), 30.0);
                    const double pd = exp(s64) / l_d[r];
                    pb = (pd > 0.01) ? f2bf((float)pd) : (u16)0;
                }
                Ps[w][(lq * 4 + r) * LDH + nt * 16 + lr] = pb;
            }
        }
        __syncthreads();   // P stores -> P b128 fragment reads

#pragma unroll
        for (int kc = 0; kc < 2; kc++) {
            const bf16x8 ap = *(const bf16x8*)(&Ps[w][lr * LDH + kc * 32 + lq * 8]);
#pragma unroll
            for (int dt = 0; dt < 4; dt++) {
                const bf16x8 bv = *(const bf16x8*)(&Vs[(dt * 16 + lr) * LDH + kc * 32 + lq * 8]);
                oacc[dt] = __builtin_amdgcn_mfma_f32_16x16x32_bf16(ap, bv, oacc[dt], 0, 0, 0);
            }
        }
    }

#pragma unroll
    for (int dt = 0; dt < 4; dt++) {
#pragma unroll
        for (int r = 0; r < 4; r++) {
            const int row = q0 + w * 16 + lq * 4 + r;
            const int d   = dt * 16 + lr;
            ao_ws[((size_t)b * S_ + row) * DM + h * HD + d] = f2bf(oacc[dt][r]);
        }
    }
}

// ---------------- fallback attention (R12 verbatim): k fp32, in-kernel splits ----------------
__global__ __launch_bounds__(256) void attn_mfma(
    const float* __restrict__ q_ws, const float* __restrict__ k_ws,
    const u16* __restrict__ vt_ws, u16* __restrict__ ao_ws)
{
    __shared__ __attribute__((aligned(16))) u16 K0s[64 * LDH], K1s[64 * LDH], K2s[64 * LDH];
    __shared__ __attribute__((aligned(16))) u16 Vs[64 * LDH];
    __shared__ __attribute__((aligned(16))) u16 Ps[4][16 * LDH];

    const int t  = threadIdx.x;
    const int w  = t >> 6, l = t & 63;
    const int lr = l & 15, lq = l >> 4;
    const int bh = blockIdx.y, b = bh >> 3, h = bh & 7;
    const int q0 = blockIdx.x * 64;

    const float* qg  = q_ws + ((size_t)bh * S_ + q0) * HD;
    const float* kg0 = k_ws + (size_t)bh * S_ * HD;
    const u16*   vb  = vt_ws + (size_t)bh * HD * S_;

#pragma unroll
    for (int i = 0; i < 4; i++) {
        const int e = t + 256 * i;
        const int row = e >> 4, c0 = (e & 15) * 4;
        const float4 f = *(const float4*)(qg + (size_t)e * 4);
        const float xv[4] = {f.x * 0.125f, f.y * 0.125f, f.z * 0.125f, f.w * 0.125f};
        u16 a0[4], a1[4], a2[4];
#pragma unroll
        for (int j = 0; j < 4; j++) split3(xv[j], a0[j], a1[j], a2[j]);
        int2 p0, p1, p2;
        p0.x = a0[0] | (a0[1] << 16); p0.y = a0[2] | (a0[3] << 16);
        p1.x = a1[0] | (a1[1] << 16); p1.y = a1[2] | (a1[3] << 16);
        p2.x = a2[0] | (a2[1] << 16); p2.y = a2[2] | (a2[3] << 16);
        *(int2*)(&K0s[row * LDH + c0]) = p0;
        *(int2*)(&K1s[row * LDH + c0]) = p1;
        *(int2*)(&K2s[row * LDH + c0]) = p2;
    }
    __syncthreads();

    bf16x8 fq0[2], fq1[2], fq2[2];
#pragma unroll
    for (int kc = 0; kc < 2; kc++) {
        const int o = (w * 16 + lr) * LDH + kc * 32 + lq * 8;
        fq0[kc] = *(const bf16x8*)(&K0s[o]);
        fq1[kc] = *(const bf16x8*)(&K1s[o]);
        fq2[kc] = *(const bf16x8*)(&K2s[o]);
    }

    const f32x4 zero4 = {0.f, 0.f, 0.f, 0.f};
    double lsum[4] = {0.0, 0.0, 0.0, 0.0};

    for (int jt = 0; jt < 32; jt++) {
        __syncthreads();
        const float* kg = kg0 + (size_t)jt * 64 * HD;
#pragma unroll
        for (int i = 0; i < 4; i++) {
            const int e = t + 256 * i;
            const int row = e >> 4, c0 = (e & 15) * 4;
            const float4 f = *(const float4*)(kg + (size_t)e * 4);
            const float xv[4] = {f.x, f.y, f.z, f.w};
            u16 a0[4], a1[4], a2[4];
#pragma unroll
            for (int j = 0; j < 4; j++) split3(xv[j], a0[j], a1[j], a2[j]);
            int2 p0, p1, p2;
            p0.x = a0[0] | (a0[1] << 16); p0.y = a0[2] | (a0[3] << 16);
            p1.x = a1[0] | (a1[1] << 16); p1.y = a1[2] | (a1[3] << 16);
            p2.x = a2[0] | (a2[1] << 16); p2.y = a2[2] | (a2[3] << 16);
            *(int2*)(&K0s[row * LDH + c0]) = p0;
            *(int2*)(&K1s[row * LDH + c0]) = p1;
            *(int2*)(&K2s[row * LDH + c0]) = p2;
        }
        __syncthreads();

#pragma unroll
        for (int nt = 0; nt < 4; nt++) {
            f32x4 aHH = zero4, aC = zero4;
#pragma unroll
            for (int kc = 0; kc < 2; kc++) {
                const int ko = (nt * 16 + lr) * LDH + kc * 32 + lq * 8;
                const bf16x8 k0 = *(const bf16x8*)(&K0s[ko]);
                const bf16x8 k1 = *(const bf16x8*)(&K1s[ko]);
                const bf16x8 k2 = *(const bf16x8*)(&K2s[ko]);
                aHH = __builtin_amdgcn_mfma_f32_16x16x32_bf16(fq0[kc], k0, aHH, 0, 0, 0);
                aC  = __builtin_amdgcn_mfma_f32_16x16x32_bf16(fq0[kc], k1, aC, 0, 0, 0);
                aC  = __builtin_amdgcn_mfma_f32_16x16x32_bf16(fq1[kc], k0, aC, 0, 0, 0);
                aC  = __builtin_amdgcn_mfma_f32_16x16x32_bf16(fq1[kc], k1, aC, 0, 0, 0);
                aC  = __builtin_amdgcn_mfma_f32_16x16x32_bf16(fq0[kc], k2, aC, 0, 0, 0);
                aC  = __builtin_amdgcn_mfma_f32_16x16x32_bf16(fq2[kc], k0, aC, 0, 0, 0);
            }
#pragma unroll
            for (int r = 0; r < 4; r++) {
                const float s = fminf(fmaxf(aHH[r] + aC[r], -30.f), 30.f);
                lsum[r] += (double)__expf(s);
            }
        }
    }
#pragma unroll
    for (int r = 0; r < 4; r++) {
#pragma unroll
        for (int off = 1; off < 16; off <<= 1)
            lsum[r] += __shfl_xor(lsum[r], off, 64);
    }
    double l_d[4]; float inv_l[4];
#pragma unroll
    for (int r = 0; r < 4; r++) { l_d[r] = lsum[r]; inv_l[r] = (float)(1.0 / lsum[r]); }

    f32x4 oacc[4];
#pragma unroll
    for (int dt = 0; dt < 4; dt++) oacc[dt] = zero4;

    for (int jt = 0; jt < 32; jt++) {
        __syncthreads();
        const float* kg = kg0 + (size_t)jt * 64 * HD;
#pragma unroll
        for (int i = 0; i < 4; i++) {
            const int e = t + 256 * i;
            const int row = e >> 4, c0 = (e & 15) * 4;
            const float4 f = *(const float4*)(kg + (size_t)e * 4);
            int2 p0;
            p0.x = f2bf(f.x) | (f2bf(f.y) << 16);
            p0.y = f2bf(f.z) | (f2bf(f.w) << 16);
            *(int2*)(&K0s[row * LDH + c0]) = p0;
        }
#pragma unroll
        for (int i = 0; i < 2; i++) {
            const int e = t + 256 * i;
            const int row = e >> 3, c0 = (e & 7) * 8;
            *(int4*)(&Vs[row * LDH + c0]) = *(const int4*)(&vb[(size_t)row * S_ + jt * 64 + c0]);
        }
        __syncthreads();

#pragma unroll
        for (int nt = 0; nt < 4; nt++) {
            f32x4 sacc = zero4;
#pragma unroll
            for (int kc = 0; kc < 2; kc++) {
                const bf16x8 k0 = *(const bf16x8*)(&K0s[(nt * 16 + lr) * LDH + kc * 32 + lq * 8]);
                sacc = __builtin_amdgcn_mfma_f32_16x16x32_bf16(fq0[kc], k0, sacc, 0, 0, 0);
            }
#pragma unroll
            for (int r = 0; r < 4; r++) {
                const float s = fminf(fmaxf(sacc[r], -30.f), 30.f);
                const float p = __expf(s) * inv_l[r];
                u16 pb;
                if (p > 0.0115f) {
                    pb = f2bf(p);
                } else if (p < 0.009f) {
                    pb = 0;
                } else {
                    const int row = q0 + w * 16 + lq * 4 + r;
                    const int col = jt * 64 + nt * 16 + lr;
                    const float* qr  = q_ws + ((size_t)bh * S_ + row) * HD;
                    const float* kcv = k_ws + ((size_t)bh * S_ + col) * HD;
                    double s64 = 0.0;
                    for (int d = 0; d < HD; d++) s64 += (double)qr[d] * (double)kcv[d];
                    s64 = fmin(fmax(s64 * 0.125, -30.0), 30.0);
                    const double pd = exp(s64) / l_d[r];
                    pb = (pd > 0.01) ? f2bf((float)pd) : (u16)0;
                }
                Ps[w][(lq * 4 + r) * LDH + nt * 16 + lr] = pb;
            }
        }
        __syncthreads();

#pragma unroll
        for (int kc = 0; kc < 2; kc++) {
            const bf16x8 ap = *(const bf16x8*)(&Ps[w][lr * LDH + kc * 32 + lq * 8]);
#pragma unroll
            for (int dt = 0; dt < 4; dt++) {
                const bf16x8 bv = *(const bf16x8*)(&Vs[(dt * 16 + lr) * LDH + kc * 32 + lq * 8]);
                oacc[dt] = __builtin_amdgcn_mfma_f32_16x16x32_bf16(ap, bv, oacc[dt], 0, 0, 0);
            }
        }
    }

#pragma unroll
    for (int dt = 0; dt < 4; dt++) {
#pragma unroll
        for (int r = 0; r < 4; r++) {
            const int row = q0 + w * 16 + lq * 4 + r;
            const int d   = dt * 16 + lr;
            ao_ws[((size_t)b * S_ + row) * DM + h * HD + d] = f2bf(oacc[dt][r]);
        }
    }
}

// ---------------- out projection: MFMA, bf16 A x 2-split W^T -> fp32 out ----------------
__global__ __launch_bounds__(256) void gemm_out_mfma(
    const u16* __restrict__ A, const u16* __restrict__ Wt0, const u16* __restrict__ Wt1,
    const float* __restrict__ bias, float* __restrict__ out)
{
    __shared__ __attribute__((aligned(16))) u16 As[128 * 32];
    __shared__ __attribute__((aligned(16))) u16 Bs0[128 * 32], Bs1[128 * 32];

    const int t  = threadIdx.x;
    const int m0 = blockIdx.y * 128, n0 = blockIdx.x * 128;
    const int w  = t >> 6, l = t & 63;
    const int wm = (w >> 1) * 64, wn = (w & 1) * 64;
    const int lr = l & 15, lq = l >> 4;

    const f32x4 zero4 = {0.f, 0.f, 0.f, 0.f};
    f32x4 acc[4][4];
#pragma unroll
    for (int i = 0; i < 4; i++)
#pragma unroll
        for (int j = 0; j < 4; j++) acc[i][j] = zero4;

    for (int k0 = 0; k0 < 512; k0 += 32) {
        __syncthreads();
#pragma unroll
        for (int i = 0; i < 2; i++) {
            const int e = t + 256 * i;
            const int r = e >> 2, c0 = (e & 3) * 8;
            *(int4*)(&As[r * 32 + c0])  = *(const int4*)(&A  [(size_t)(m0 + r) * 512 + k0 + c0]);
            *(int4*)(&Bs0[r * 32 + c0]) = *(const int4*)(&Wt0[(size_t)(n0 + r) * 512 + k0 + c0]);
            *(int4*)(&Bs1[r * 32 + c0]) = *(const int4*)(&Wt1[(size_t)(n0 + r) * 512 + k0 + c0]);
        }
        __syncthreads();

#pragma unroll
        for (int i = 0; i < 4; i++) {
            const bf16x8 a = *(const bf16x8*)(&As[(wm + i * 16 + lr) * 32 + lq * 8]);
#pragma unroll
            for (int j = 0; j < 4; j++) {
                const int bo = (wn + j * 16 + lr) * 32 + lq * 8;
                const bf16x8 b0 = *(const bf16x8*)(&Bs0[bo]);
                const bf16x8 b1 = *(const bf16x8*)(&Bs1[bo]);
                f32x4 c = acc[i][j];
                c = __builtin_amdgcn_mfma_f32_16x16x32_bf16(a, b0, c, 0, 0, 0);
                c = __builtin_amdgcn_mfma_f32_16x16x32_bf16(a, b1, c, 0, 0, 0);
                acc[i][j] = c;
            }
        }
    }

#pragma unroll
    for (int j = 0; j < 4; j++) {
        const int n = n0 + wn + j * 16 + lr;
        const float bv = bias[n];
#pragma unroll
        for (int i = 0; i < 4; i++) {
#pragma unroll
            for (int r = 0; r < 4; r++) {
                const int m = m0 + wm + i * 16 + lq * 4 + r;
                out[(size_t)m * 512 + n] = acc[i][j][r] + bv;
            }
        }
    }
}

// ---------------- launch ----------------
extern "C" void kernel_launch(void* const* d_in, const int* in_sizes, int n_in,
                              void* d_out, int out_size, void* d_ws, size_t ws_size,
                              hipStream_t stream) {
    const float* x = nullptr; const float* Wqkv = nullptr; const float* bqkv = nullptr;
    const float* Wout = nullptr; const float* bout = nullptr;
    for (int i = 0; i < n_in; i++) {
        switch (in_sizes[i]) {
            case 4194304: x    = (const float*)d_in[i]; break;
            case 786432:  Wqkv = (const float*)d_in[i]; break;
            case 1536:    bqkv = (const float*)d_in[i]; break;
            case 262144:  Wout = (const float*)d_in[i]; break;
            case 512:     bout = (const float*)d_in[i]; break;
            default: break;
        }
    }
    if (!x)    x    = (const float*)d_in[0];
    if (!Wqkv) Wqkv = (const float*)d_in[1];
    if (!bqkv) bqkv = (const float*)d_in[2];
    if (!Wout) Wout = (const float*)d_in[3];
    if (!bout) bout = (const float*)d_in[4];

    float* out = (float*)d_out;
    char* ws = (char*)d_ws;
    const bool fast = (ws_size >= (56ull << 20));

    if (fast) {
        // fast layout (56 MB): q fp32 0-16 | k0 16-24 | k1 24-32 | k2 32-40 | vt 40-48 | ao 48-56
        float* q_ws  = (float*)(ws);
        u16* k0g = (u16*)(ws + (16ull << 20));
        u16* k1g = (u16*)(ws + (24ull << 20));
        u16* k2g = (u16*)(ws + (32ull << 20));
        u16* vt_ws = (u16*)(ws + (40ull << 20));
        u16* ao_ws = (u16*)(ws + (48ull << 20));
        u16* wt0 = (u16*)(ws + (48ull << 20));                 // ao region, dead pre-attn
        u16* wt1 = (u16*)(ws + (48ull << 20) + 1572864);
        u16* wt2 = (u16*)(ws + (48ull << 20) + 3145728);
        u16* wo0 = (u16*)(ws + (40ull << 20));                 // vt region, dead post-attn
        u16* wo1 = (u16*)(ws + (40ull << 20) + 524288);

        prep_split_wT<<<3072, 256, 0, stream>>>(Wqkv, 1536, 1536 * 512, wt0, wt1, wt2);
        gemm_qkv_mfma<<<dim3(12, 64), 256, 0, stream>>>(
            x, wt0, wt1, wt2, bqkv, q_ws, nullptr, k0g, k1g, k2g, vt_ws, 1);
        attn_pre<<<dim3(32, BHN), 256, 0, stream>>>(q_ws, k0g, k1g, k2g, vt_ws, ao_ws);
        prep_split_wT<<<1024, 256, 0, stream>>>(Wout, 512, 512 * 512, wo0, wo1, nullptr);
        gemm_out_mfma<<<dim3(4, 64), 256, 0, stream>>>(ao_ws, wo0, wo1, bout, out);
    } else {
        // safe layout (48 MB, R12): q 0-16 | k 16-32 | vt 32-40 | ao 40-48
        float* q_ws  = (float*)(ws);
        float* k_ws  = (float*)(ws + (16ull << 20));
        u16* vt_ws = (u16*)(ws + (32ull << 20));
        u16* ao_ws = (u16*)(ws + (40ull << 20));
        u16* wt0 = (u16*)(ws + (40ull << 20));
        u16* wt1 = (u16*)(ws + (40ull << 20) + 1572864);
        u16* wt2 = (u16*)(ws + (40ull << 20) + 3145728);
        u16* wo0 = (u16*)(ws + (32ull << 20));
        u16* wo1 = (u16*)(ws + (32ull << 20) + 524288);

        prep_split_wT<<<3072, 256, 0, stream>>>(Wqkv, 1536, 1536 * 512, wt0, wt1, wt2);
        gemm_qkv_mfma<<<dim3(12, 64), 256, 0, stream>>>(
            x, wt0, wt1, wt2, bqkv, q_ws, k_ws, nullptr, nullptr, nullptr, vt_ws, 0);
        attn_mfma<<<dim3(32, BHN), 256, 0, stream>>>(q_ws, k_ws, vt_ws, ao_ws);
        prep_split_wT<<<1024, 256, 0, stream>>>(Wout, 512, 512 * 512, wo0, wo1, nullptr);
        gemm_out_mfma<<<dim3(4, 64), 256, 0, stream>>>(ao_ws, wo0, wo1, bout, out);
    }
}

// Round 14
// 509.935 us; speedup vs baseline: 1.3633x; 1.3633x over previous
//
#include <hip/hip_runtime.h>

// ---------------- problem constants ----------------
#define S_   2048
#define DM   512
#define HD   64
#define BHN  32

typedef unsigned short u16;
typedef __bf16 bf16x8 __attribute__((ext_vector_type(8)));
typedef float  f32x4  __attribute__((ext_vector_type(4)));

__device__ __forceinline__ float bf2f(u16 u) {
    union { unsigned int i; float f; } v; v.i = ((unsigned int)u) << 16; return v.f;
}
__device__ __forceinline__ u16 f2bf(float f) {
    union { float f; unsigned int i; } v; v.f = f;
    unsigned int i = v.i;
    return (u16)((i + 0x7FFFu + ((i >> 16) & 1u)) >> 16);   // RNE
}
// 3-term bf16 split: x ~= b0+b1+b2 (residual ~2^-27 |x|)
__device__ __forceinline__ void split3(float x, u16& b0, u16& b1, u16& b2) {
    b0 = f2bf(x);
    const float r0 = x - bf2f(b0);
    b1 = f2bf(r0);
    const float r1 = r0 - bf2f(b1);
    b2 = f2bf(r1);
}

// ---------------- prep: W[k][n] fp32 -> transposed bf16 splits [n][k] ----------------
__global__ __launch_bounds__(256) void prep_split_wT(
    const float* __restrict__ W, int N, int total,
    u16* __restrict__ w0, u16* __restrict__ w1, u16* __restrict__ w2)
{
    for (int idx = blockIdx.x * 256 + threadIdx.x; idx < total; idx += gridDim.x * 256) {
        const int n = idx >> 9, k = idx & 511;      // K = 512
        u16 a0, a1, a2;
        split3(W[(size_t)k * N + n], a0, a1, a2);
        w0[idx] = a0; w1[idx] = a1;
        if (w2) w2[idx] = a2;
    }
}

// ---------------- QKV GEMM: MFMA, 3-split x, 3-split W^T (R12 verbatim) ----------------
__global__ __launch_bounds__(256) void gemm_qkv_mfma(
    const float* __restrict__ A, const u16* __restrict__ Wt0, const u16* __restrict__ Wt1,
    const u16* __restrict__ Wt2, const float* __restrict__ bias,
    float* __restrict__ qh, float* __restrict__ kh, u16* __restrict__ vt)
{
    __shared__ __attribute__((aligned(16))) u16 As0[128 * 32], As1[128 * 32], As2[128 * 32];
    __shared__ __attribute__((aligned(16))) u16 Bs0[128 * 32], Bs1[128 * 32], Bs2[128 * 32];

    const int t  = threadIdx.x;
    const int m0 = blockIdx.y * 128, n0 = blockIdx.x * 128;
    const int w  = t >> 6, l = t & 63;
    const int wm = (w >> 1) * 64, wn = (w & 1) * 64;
    const int lr = l & 15, lq = l >> 4;

    const f32x4 zero4 = {0.f, 0.f, 0.f, 0.f};
    f32x4 acc[4][4];
#pragma unroll
    for (int i = 0; i < 4; i++)
#pragma unroll
        for (int j = 0; j < 4; j++) acc[i][j] = zero4;

    for (int k0 = 0; k0 < 512; k0 += 32) {
        __syncthreads();
#pragma unroll
        for (int i = 0; i < 4; i++) {
            const int e = t + 256 * i;
            const int r = e >> 3, c4 = (e & 7) * 4;
            const float4 f = *(const float4*)(&A[(size_t)(m0 + r) * 512 + k0 + c4]);
            const float xv[4] = {f.x, f.y, f.z, f.w};
            u16 a0[4], a1[4], a2[4];
#pragma unroll
            for (int j = 0; j < 4; j++) split3(xv[j], a0[j], a1[j], a2[j]);
            int2 p0, p1, p2;
            p0.x = a0[0] | (a0[1] << 16); p0.y = a0[2] | (a0[3] << 16);
            p1.x = a1[0] | (a1[1] << 16); p1.y = a1[2] | (a1[3] << 16);
            p2.x = a2[0] | (a2[1] << 16); p2.y = a2[2] | (a2[3] << 16);
            *(int2*)(&As0[r * 32 + c4]) = p0;
            *(int2*)(&As1[r * 32 + c4]) = p1;
            *(int2*)(&As2[r * 32 + c4]) = p2;
        }
#pragma unroll
        for (int i = 0; i < 2; i++) {
            const int e = t + 256 * i;
            const int r = e >> 2, c0 = (e & 3) * 8;
            *(int4*)(&Bs0[r * 32 + c0]) = *(const int4*)(&Wt0[(size_t)(n0 + r) * 512 + k0 + c0]);
            *(int4*)(&Bs1[r * 32 + c0]) = *(const int4*)(&Wt1[(size_t)(n0 + r) * 512 + k0 + c0]);
            *(int4*)(&Bs2[r * 32 + c0]) = *(const int4*)(&Wt2[(size_t)(n0 + r) * 512 + k0 + c0]);
        }
        __syncthreads();

#pragma unroll
        for (int i = 0; i < 4; i++) {
            const int ao = (wm + i * 16 + lr) * 32 + lq * 8;
            const bf16x8 a0 = *(const bf16x8*)(&As0[ao]);
            const bf16x8 a1 = *(const bf16x8*)(&As1[ao]);
            const bf16x8 a2 = *(const bf16x8*)(&As2[ao]);
#pragma unroll
            for (int j = 0; j < 4; j++) {
                const int bo = (wn + j * 16 + lr) * 32 + lq * 8;
                const bf16x8 b0 = *(const bf16x8*)(&Bs0[bo]);
                const bf16x8 b1 = *(const bf16x8*)(&Bs1[bo]);
                const bf16x8 b2 = *(const bf16x8*)(&Bs2[bo]);
                f32x4 c = acc[i][j];
                c = __builtin_amdgcn_mfma_f32_16x16x32_bf16(a0, b0, c, 0, 0, 0);
                c = __builtin_amdgcn_mfma_f32_16x16x32_bf16(a0, b1, c, 0, 0, 0);
                c = __builtin_amdgcn_mfma_f32_16x16x32_bf16(a1, b0, c, 0, 0, 0);
                c = __builtin_amdgcn_mfma_f32_16x16x32_bf16(a1, b1, c, 0, 0, 0);
                c = __builtin_amdgcn_mfma_f32_16x16x32_bf16(a0, b2, c, 0, 0, 0);
                c = __builtin_amdgcn_mfma_f32_16x16x32_bf16(a2, b0, c, 0, 0, 0);
                acc[i][j] = c;
            }
        }
    }

#pragma unroll
    for (int j = 0; j < 4; j++) {
        const int n = n0 + wn + j * 16 + lr;
        const float bv = bias[n];
        const int part = n >> 9, within = n & 511;
        const int h = within >> 6, d = within & 63;
#pragma unroll
        for (int i = 0; i < 4; i++) {
#pragma unroll
            for (int r = 0; r < 4; r++) {
                const int m = m0 + wm + i * 16 + lq * 4 + r;
                const int b = m >> 11, ns = m & 2047;
                const float val = acc[i][j][r] + bv;
                if (part == 0)
                    qh[(((size_t)(b * 8 + h)) * S_ + ns) * HD + d] = val;
                else if (part == 1)
                    kh[(((size_t)(b * 8 + h)) * S_ + ns) * HD + d] = val;
                else
                    vt[(((size_t)(b * 8 + h)) * HD + d) * S_ + ns] = f2bf(val);
            }
        }
    }
}

// ---------------- attention: 128 q-rows/block, in-kernel K splits ----------------
// 4 waves; wave w owns rows [w*32, w*32+32) as two 16-row fragments (i=0,1).
#define LDH 72

__global__ __launch_bounds__(256) void attn_mfma128(
    const float* __restrict__ q_ws, const float* __restrict__ k_ws,
    const u16* __restrict__ vt_ws, u16* __restrict__ ao_ws)
{
    __shared__ __attribute__((aligned(16))) u16 K0s[64 * LDH], K1s[64 * LDH], K2s[64 * LDH];
    __shared__ __attribute__((aligned(16))) u16 Vs[64 * LDH];
    __shared__ __attribute__((aligned(16))) u16 Ps[4][16 * LDH];

    const int t  = threadIdx.x;
    const int w  = t >> 6, l = t & 63;
    const int lr = l & 15, lq = l >> 4;
    const int bh = blockIdx.y, b = bh >> 3, h = bh & 7;
    const int q0 = blockIdx.x * 128;

    const float* qg  = q_ws + ((size_t)bh * S_ + q0) * HD;
    const float* kg0 = k_ws + (size_t)bh * S_ * HD;
    const u16*   vb  = vt_ws + (size_t)bh * HD * S_;

    // ---- stage Q 3-split (scale folded) in two 64-row halves through K buffers ----
    bf16x8 fq0[2][2], fq1[2][2], fq2[2][2];    // [i][kc]
#pragma unroll
    for (int h2 = 0; h2 < 2; h2++) {
        __syncthreads();
#pragma unroll
        for (int i = 0; i < 4; i++) {
            const int e = t + 256 * i;                 // 1024 float4s over 64x64
            const int row = e >> 4, c0 = (e & 15) * 4;
            const float4 f = *(const float4*)(qg + (size_t)h2 * 4096 + (size_t)e * 4);
            const float xv[4] = {f.x * 0.125f, f.y * 0.125f, f.z * 0.125f, f.w * 0.125f};
            u16 a0[4], a1[4], a2[4];
#pragma unroll
            for (int j = 0; j < 4; j++) split3(xv[j], a0[j], a1[j], a2[j]);
            int2 p0, p1, p2;
            p0.x = a0[0] | (a0[1] << 16); p0.y = a0[2] | (a0[3] << 16);
            p1.x = a1[0] | (a1[1] << 16); p1.y = a1[2] | (a1[3] << 16);
            p2.x = a2[0] | (a2[1] << 16); p2.y = a2[2] | (a2[3] << 16);
            *(int2*)(&K0s[row * LDH + c0]) = p0;
            *(int2*)(&K1s[row * LDH + c0]) = p1;
            *(int2*)(&K2s[row * LDH + c0]) = p2;
        }
        __syncthreads();
        if ((w >> 1) == h2) {
#pragma unroll
            for (int i = 0; i < 2; i++) {
#pragma unroll
                for (int kc = 0; kc < 2; kc++) {
                    const int o = ((w & 1) * 32 + i * 16 + lr) * LDH + kc * 32 + lq * 8;
                    fq0[i][kc] = *(const bf16x8*)(&K0s[o]);
                    fq1[i][kc] = *(const bf16x8*)(&K1s[o]);
                    fq2[i][kc] = *(const bf16x8*)(&K2s[o]);
                }
            }
        }
    }

    const f32x4 zero4 = {0.f, 0.f, 0.f, 0.f};
    double lsum[2][4];
#pragma unroll
    for (int i = 0; i < 2; i++)
#pragma unroll
        for (int r = 0; r < 4; r++) lsum[i][r] = 0.0;

    // ---- pass A: denominator via 3-split scores ----
    for (int jt = 0; jt < 32; jt++) {
        __syncthreads();
        const float* kg = kg0 + (size_t)jt * 64 * HD;
#pragma unroll
        for (int i = 0; i < 4; i++) {
            const int e = t + 256 * i;
            const int row = e >> 4, c0 = (e & 15) * 4;
            const float4 f = *(const float4*)(kg + (size_t)e * 4);
            const float xv[4] = {f.x, f.y, f.z, f.w};
            u16 a0[4], a1[4], a2[4];
#pragma unroll
            for (int j = 0; j < 4; j++) split3(xv[j], a0[j], a1[j], a2[j]);
            int2 p0, p1, p2;
            p0.x = a0[0] | (a0[1] << 16); p0.y = a0[2] | (a0[3] << 16);
            p1.x = a1[0] | (a1[1] << 16); p1.y = a1[2] | (a1[3] << 16);
            p2.x = a2[0] | (a2[1] << 16); p2.y = a2[2] | (a2[3] << 16);
            *(int2*)(&K0s[row * LDH + c0]) = p0;
            *(int2*)(&K1s[row * LDH + c0]) = p1;
            *(int2*)(&K2s[row * LDH + c0]) = p2;
        }
        __syncthreads();

#pragma unroll
        for (int i = 0; i < 2; i++) {
#pragma unroll
            for (int nt = 0; nt < 4; nt++) {
                f32x4 aHH = zero4, aC = zero4;
#pragma unroll
                for (int kc = 0; kc < 2; kc++) {
                    const int ko = (nt * 16 + lr) * LDH + kc * 32 + lq * 8;
                    const bf16x8 k0 = *(const bf16x8*)(&K0s[ko]);
                    const bf16x8 k1 = *(const bf16x8*)(&K1s[ko]);
                    const bf16x8 k2 = *(const bf16x8*)(&K2s[ko]);
                    aHH = __builtin_amdgcn_mfma_f32_16x16x32_bf16(fq0[i][kc], k0, aHH, 0, 0, 0);
                    aC  = __builtin_amdgcn_mfma_f32_16x16x32_bf16(fq0[i][kc], k1, aC, 0, 0, 0);
                    aC  = __builtin_amdgcn_mfma_f32_16x16x32_bf16(fq1[i][kc], k0, aC, 0, 0, 0);
                    aC  = __builtin_amdgcn_mfma_f32_16x16x32_bf16(fq1[i][kc], k1, aC, 0, 0, 0);
                    aC  = __builtin_amdgcn_mfma_f32_16x16x32_bf16(fq0[i][kc], k2, aC, 0, 0, 0);
                    aC  = __builtin_amdgcn_mfma_f32_16x16x32_bf16(fq2[i][kc], k0, aC, 0, 0, 0);
                }
#pragma unroll
                for (int r = 0; r < 4; r++) {
                    const float s = fminf(fmaxf(aHH[r] + aC[r], -30.f), 30.f);
                    lsum[i][r] += (double)__expf(s);
                }
            }
        }
    }
#pragma unroll
    for (int i = 0; i < 2; i++)
#pragma unroll
        for (int r = 0; r < 4; r++) {
#pragma unroll
            for (int off = 1; off < 16; off <<= 1)
                lsum[i][r] += __shfl_xor(lsum[i][r], off, 64);
        }
    double l_d[2][4]; float inv_l[2][4];
#pragma unroll
    for (int i = 0; i < 2; i++)
#pragma unroll
        for (int r = 0; r < 4; r++) {
            l_d[i][r] = lsum[i][r];
            inv_l[i][r] = (float)(1.0 / lsum[i][r]);
        }

    f32x4 oacc[2][4];
#pragma unroll
    for (int i = 0; i < 2; i++)
#pragma unroll
        for (int dt = 0; dt < 4; dt++) oacc[i][dt] = zero4;

    // ---- pass B: bf16 scores, band [0.009,0.0115] -> fp64 refine, MFMA PV ----
    for (int jt = 0; jt < 32; jt++) {
        __syncthreads();
        const float* kg = kg0 + (size_t)jt * 64 * HD;
#pragma unroll
        for (int i = 0; i < 4; i++) {               // K hi only
            const int e = t + 256 * i;
            const int row = e >> 4, c0 = (e & 15) * 4;
            const float4 f = *(const float4*)(kg + (size_t)e * 4);
            int2 p0;
            p0.x = f2bf(f.x) | (f2bf(f.y) << 16);
            p0.y = f2bf(f.z) | (f2bf(f.w) << 16);
            *(int2*)(&K0s[row * LDH + c0]) = p0;
        }
#pragma unroll
        for (int i = 0; i < 2; i++) {               // V^T tile [d][key]
            const int e = t + 256 * i;
            const int row = e >> 3, c0 = (e & 7) * 8;
            *(int4*)(&Vs[row * LDH + c0]) = *(const int4*)(&vb[(size_t)row * S_ + jt * 64 + c0]);
        }
        __syncthreads();

#pragma unroll
        for (int i = 0; i < 2; i++) {
#pragma unroll
            for (int nt = 0; nt < 4; nt++) {
                f32x4 sacc = zero4;
#pragma unroll
                for (int kc = 0; kc < 2; kc++) {
                    const bf16x8 k0 = *(const bf16x8*)(&K0s[(nt * 16 + lr) * LDH + kc * 32 + lq * 8]);
                    sacc = __builtin_amdgcn_mfma_f32_16x16x32_bf16(fq0[i][kc], k0, sacc, 0, 0, 0);
                }
#pragma unroll
                for (int r = 0; r < 4; r++) {
                    const float s = fminf(fmaxf(sacc[r], -30.f), 30.f);
                    const float p = __expf(s) * inv_l[i][r];
                    u16 pb;
                    if (p > 0.0115f) {
                        pb = f2bf(p);
                    } else if (p < 0.009f) {
                        pb = 0;
                    } else {
                        const int row = q0 + w * 32 + i * 16 + lq * 4 + r;
                        const int col = jt * 64 + nt * 16 + lr;
                        const float* qr  = q_ws + ((size_t)bh * S_ + row) * HD;
                        const float* kcv = k_ws + ((size_t)bh * S_ + col) * HD;
                        double s64 = 0.0;
                        for (int d = 0; d < HD; d++) s64 += (double)qr[d] * (double)kcv[d];
                        s64 = fmin(fmax(s64 * 0.125, -30.0), 30.0);
                        const double pd = exp(s64) / l_d[i][r];
                        pb = (pd > 0.01) ? f2bf((float)pd) : (u16)0;
                    }
                    Ps[w][(lq * 4 + r) * LDH + nt * 16 + lr] = pb;
                }
            }
            __syncthreads();   // P stores -> P b128 reads (TBAA fence)
#pragma unroll
            for (int kc = 0; kc < 2; kc++) {
                const bf16x8 ap = *(const bf16x8*)(&Ps[w][lr * LDH + kc * 32 + lq * 8]);
#pragma unroll
                for (int dt = 0; dt < 4; dt++) {
                    const bf16x8 bv = *(const bf16x8*)(&Vs[(dt * 16 + lr) * LDH + kc * 32 + lq * 8]);
                    oacc[i][dt] = __builtin_amdgcn_mfma_f32_16x16x32_bf16(ap, bv, oacc[i][dt], 0, 0, 0);
                }
            }
            __syncthreads();   // P reads done before i=1 overwrites (and next jt staging)
        }
    }

    // epilogue
#pragma unroll
    for (int i = 0; i < 2; i++)
#pragma unroll
        for (int dt = 0; dt < 4; dt++) {
#pragma unroll
            for (int r = 0; r < 4; r++) {
                const int row = q0 + w * 32 + i * 16 + lq * 4 + r;
                const int d   = dt * 16 + lr;
                ao_ws[((size_t)b * S_ + row) * DM + h * HD + d] = f2bf(oacc[i][dt][r]);
            }
        }
}

// ---------------- out projection: MFMA, bf16 A x 2-split W^T -> fp32 out ----------------
__global__ __launch_bounds__(256) void gemm_out_mfma(
    const u16* __restrict__ A, const u16* __restrict__ Wt0, const u16* __restrict__ Wt1,
    const float* __restrict__ bias, float* __restrict__ out)
{
    __shared__ __attribute__((aligned(16))) u16 As[128 * 32];
    __shared__ __attribute__((aligned(16))) u16 Bs0[128 * 32], Bs1[128 * 32];

    const int t  = threadIdx.x;
    const int m0 = blockIdx.y * 128, n0 = blockIdx.x * 128;
    const int w  = t >> 6, l = t & 63;
    const int wm = (w >> 1) * 64, wn = (w & 1) * 64;
    const int lr = l & 15, lq = l >> 4;

    const f32x4 zero4 = {0.f, 0.f, 0.f, 0.f};
    f32x4 acc[4][4];
#pragma unroll
    for (int i = 0; i < 4; i++)
#pragma unroll
        for (int j = 0; j < 4; j++) acc[i][j] = zero4;

    for (int k0 = 0; k0 < 512; k0 += 32) {
        __syncthreads();
#pragma unroll
        for (int i = 0; i < 2; i++) {
            const int e = t + 256 * i;
            const int r = e >> 2, c0 = (e & 3) * 8;
            *(int4*)(&As[r * 32 + c0])  = *(const int4*)(&A  [(size_t)(m0 + r) * 512 + k0 + c0]);
            *(int4*)(&Bs0[r * 32 + c0]) = *(const int4*)(&Wt0[(size_t)(n0 + r) * 512 + k0 + c0]);
            *(int4*)(&Bs1[r * 32 + c0]) = *(const int4*)(&Wt1[(size_t)(n0 + r) * 512 + k0 + c0]);
        }
        __syncthreads();

#pragma unroll
        for (int i = 0; i < 4; i++) {
            const bf16x8 a = *(const bf16x8*)(&As[(wm + i * 16 + lr) * 32 + lq * 8]);
#pragma unroll
            for (int j = 0; j < 4; j++) {
                const int bo = (wn + j * 16 + lr) * 32 + lq * 8;
                const bf16x8 b0 = *(const bf16x8*)(&Bs0[bo]);
                const bf16x8 b1 = *(const bf16x8*)(&Bs1[bo]);
                f32x4 c = acc[i][j];
                c = __builtin_amdgcn_mfma_f32_16x16x32_bf16(a, b0, c, 0, 0, 0);
                c = __builtin_amdgcn_mfma_f32_16x16x32_bf16(a, b1, c, 0, 0, 0);
                acc[i][j] = c;
            }
        }
    }

#pragma unroll
    for (int j = 0; j < 4; j++) {
        const int n = n0 + wn + j * 16 + lr;
        const float bv = bias[n];
#pragma unroll
        for (int i = 0; i < 4; i++) {
#pragma unroll
            for (int r = 0; r < 4; r++) {
                const int m = m0 + wm + i * 16 + lq * 4 + r;
                out[(size_t)m * 512 + n] = acc[i][j][r] + bv;
            }
        }
    }
}

// ---------------- launch ----------------
extern "C" void kernel_launch(void* const* d_in, const int* in_sizes, int n_in,
                              void* d_out, int out_size, void* d_ws, size_t ws_size,
                              hipStream_t stream) {
    const float* x = nullptr; const float* Wqkv = nullptr; const float* bqkv = nullptr;
    const float* Wout = nullptr; const float* bout = nullptr;
    for (int i = 0; i < n_in; i++) {
        switch (in_sizes[i]) {
            case 4194304: x    = (const float*)d_in[i]; break;
            case 786432:  Wqkv = (const float*)d_in[i]; break;
            case 1536:    bqkv = (const float*)d_in[i]; break;
            case 262144:  Wout = (const float*)d_in[i]; break;
            case 512:     bout = (const float*)d_in[i]; break;
            default: break;
        }
    }
    if (!x)    x    = (const float*)d_in[0];
    if (!Wqkv) Wqkv = (const float*)d_in[1];
    if (!bqkv) bqkv = (const float*)d_in[2];
    if (!Wout) Wout = (const float*)d_in[3];
    if (!bout) bout = (const float*)d_in[4];

    float* out = (float*)d_out;

    // R12 layout (48 MB): q 0-16 | k 16-32 | vt 32-40 | ao 40-48
    char* ws = (char*)d_ws;
    float* q_ws  = (float*)(ws);
    float* k_ws  = (float*)(ws + (16ull << 20));
    u16* vt_ws = (u16*)(ws + (32ull << 20));
    u16* ao_ws = (u16*)(ws + (40ull << 20));
    u16* wt0 = (u16*)(ws + (40ull << 20));                 // ao region, dead pre-attn
    u16* wt1 = (u16*)(ws + (40ull << 20) + 1572864);
    u16* wt2 = (u16*)(ws + (40ull << 20) + 3145728);
    u16* wo0 = (u16*)(ws + (32ull << 20));                 // vt region, dead post-attn
    u16* wo1 = (u16*)(ws + (32ull << 20) + 524288);

    prep_split_wT<<<3072, 256, 0, stream>>>(Wqkv, 1536, 1536 * 512, wt0, wt1, wt2);
    gemm_qkv_mfma<<<dim3(12, 64), 256, 0, stream>>>(
        x, wt0, wt1, wt2, bqkv, q_ws, k_ws, vt_ws);
    attn_mfma128<<<dim3(16, BHN), 256, 0, stream>>>(q_ws, k_ws, vt_ws, ao_ws);
    prep_split_wT<<<1024, 256, 0, stream>>>(Wout, 512, 512 * 512, wo0, wo1, nullptr);
    gemm_out_mfma<<<dim3(4, 64), 256, 0, stream>>>(ao_ws, wo0, wo1, bout, out);
}